// Round 1
// baseline (20572.830 us; speedup 1.0000x reference)
//
#include <hip/hip_runtime.h>

// Problem constants (match reference)
#define NB 512   // batch
#define NT 512   // time
#define NI 128   // input dim
#define NH 256   // hidden dim
#define NG 1024  // 4*NH gate rows
#define NKW 384  // NI + NH fused K
#define EPSV 1e-5f

__device__ __forceinline__ unsigned short f32_to_bf16(float f) {
  unsigned int u = __float_as_uint(f);
  u += 0x7fffu + ((u >> 16) & 1u);   // round-to-nearest-even
  return (unsigned short)(u >> 16);
}
__device__ __forceinline__ float bf_lo(unsigned int u) { return __uint_as_float(u << 16); }
__device__ __forceinline__ float bf_hi(unsigned int u) { return __uint_as_float(u & 0xffff0000u); }

// Fuse W_ih (NG x NI) and W_hh (NG x NH) into bf16 Wc (NG x NKW), and bsum = b_ih + b_hh.
__global__ void prep_kernel(const float* __restrict__ W_ih, const float* __restrict__ W_hh,
                            const float* __restrict__ b_ih, const float* __restrict__ b_hh,
                            unsigned short* __restrict__ Wc, float* __restrict__ bsum) {
  int idx = blockIdx.x * blockDim.x + threadIdx.x;
  if (idx < NG * NKW) {
    int r = idx / NKW;
    int k = idx - r * NKW;
    float w = (k < NI) ? W_ih[r * NI + k] : W_hh[r * NH + (k - NI)];
    Wc[idx] = f32_to_bf16(w);
  }
  if (idx < NG) bsum[idx] = b_ih[idx] + b_hh[idx];
}

// One block per batch element. 256 threads; thread j owns hidden index j.
// Per step: gates[q*NH+j] = bsum + Wc[q*NH+j, :] . [x_t | h]  (bf16 weights, f32 acc)
__global__ __launch_bounds__(256, 2)
void lstm_ln_kernel(const float* __restrict__ X, const int* __restrict__ lengths,
                    const unsigned short* __restrict__ Wc, const float* __restrict__ bsum,
                    const float* __restrict__ gamma, const float* __restrict__ beta,
                    float* __restrict__ out) {
  const int b = blockIdx.x;
  const int j = threadIdx.x;

  __shared__ float xh[NKW];   // [0,NI) = x_t, [NI,NKW) = h
  __shared__ float red[8];

  const int len = lengths[b];

  const uint4* __restrict__ w0 = (const uint4*)(Wc + (size_t)(0 * NH + j) * NKW);
  const uint4* __restrict__ w1 = (const uint4*)(Wc + (size_t)(1 * NH + j) * NKW);
  const uint4* __restrict__ w2 = (const uint4*)(Wc + (size_t)(2 * NH + j) * NKW);
  const uint4* __restrict__ w3 = (const uint4*)(Wc + (size_t)(3 * NH + j) * NKW);
  const float bs0 = bsum[0 * NH + j];
  const float bs1 = bsum[1 * NH + j];
  const float bs2 = bsum[2 * NH + j];
  const float bs3 = bsum[3 * NH + j];

  float c = 0.f, hn = 0.f;
  xh[NI + j] = 0.f;

  const float* __restrict__ xrow = X + (size_t)b * NT * NI;

  for (int t = 0; t < len; ++t) {
    if (j < NI) xh[j] = xrow[(size_t)t * NI + j];
    __syncthreads();  // x_t staged AND h from prev step visible

    float a0 = bs0, a1 = bs1, a2 = bs2, a3 = bs3;
    const float4* xv = (const float4*)xh;
#pragma unroll 8
    for (int kk = 0; kk < NKW / 8; ++kk) {   // 48 iters, 8 K-elements each
      uint4 u0 = w0[kk], u1 = w1[kk], u2 = w2[kk], u3 = w3[kk];
      float4 xa = xv[2 * kk];
      float4 xb = xv[2 * kk + 1];
      a0 += bf_lo(u0.x) * xa.x + bf_hi(u0.x) * xa.y + bf_lo(u0.y) * xa.z + bf_hi(u0.y) * xa.w
          + bf_lo(u0.z) * xb.x + bf_hi(u0.z) * xb.y + bf_lo(u0.w) * xb.z + bf_hi(u0.w) * xb.w;
      a1 += bf_lo(u1.x) * xa.x + bf_hi(u1.x) * xa.y + bf_lo(u1.y) * xa.z + bf_hi(u1.y) * xa.w
          + bf_lo(u1.z) * xb.x + bf_hi(u1.z) * xb.y + bf_lo(u1.w) * xb.z + bf_hi(u1.w) * xb.w;
      a2 += bf_lo(u2.x) * xa.x + bf_hi(u2.x) * xa.y + bf_lo(u2.y) * xa.z + bf_hi(u2.y) * xa.w
          + bf_lo(u2.z) * xb.x + bf_hi(u2.z) * xb.y + bf_lo(u2.w) * xb.z + bf_hi(u2.w) * xb.w;
      a3 += bf_lo(u3.x) * xa.x + bf_hi(u3.x) * xa.y + bf_lo(u3.y) * xa.z + bf_hi(u3.y) * xa.w
          + bf_lo(u3.z) * xb.x + bf_hi(u3.z) * xb.y + bf_lo(u3.w) * xb.z + bf_hi(u3.w) * xb.w;
    }

    // gate order [i, f, g, o]
    float ig = 1.f / (1.f + __expf(-a0));
    float fg = 1.f / (1.f + __expf(-a1));
    float gg = 1.f - 2.f / (1.f + __expf(2.f * a2));  // tanh
    float og = 1.f / (1.f + __expf(-a3));
    c = fg * c + ig * gg;
    float tc = 1.f - 2.f / (1.f + __expf(2.f * c));   // tanh(c)
    hn = og * tc;

    __syncthreads();  // everyone done reading old h
    xh[NI + j] = hn;
  }

  // ---- LayerNorm over H=256 (4 waves) ----
  float h = hn;
  float s = h, sq = h * h;
#pragma unroll
  for (int off = 32; off > 0; off >>= 1) {
    s += __shfl_xor(s, off);
    sq += __shfl_xor(sq, off);
  }
  int wid = j >> 6;
  int lane = j & 63;
  if (lane == 0) { red[wid] = s; red[4 + wid] = sq; }
  __syncthreads();
  if (j == 0) {
    float S = red[0] + red[1] + red[2] + red[3];
    float Q = red[4] + red[5] + red[6] + red[7];
    float mu = S * (1.f / NH);
    float var = Q * (1.f / NH) - mu * mu;
    red[0] = mu;
    red[1] = rsqrtf(var + EPSV);
  }
  __syncthreads();
  float mu = red[0], rstd = red[1];
  out[(size_t)b * NH + j] = (h - mu) * rstd * gamma[j] + beta[j];
}

extern "C" void kernel_launch(void* const* d_in, const int* in_sizes, int n_in,
                              void* d_out, int out_size, void* d_ws, size_t ws_size,
                              hipStream_t stream) {
  const float* X       = (const float*)d_in[0];
  const int*   lengths = (const int*)d_in[1];
  const float* W_ih    = (const float*)d_in[2];
  const float* W_hh    = (const float*)d_in[3];
  const float* b_ih    = (const float*)d_in[4];
  const float* b_hh    = (const float*)d_in[5];
  const float* gamma   = (const float*)d_in[6];
  const float* beta    = (const float*)d_in[7];
  float* out = (float*)d_out;

  unsigned short* Wc = (unsigned short*)d_ws;
  float* bsum = (float*)((char*)d_ws + (size_t)NG * NKW * sizeof(unsigned short));

  int total = NG * NKW;
  prep_kernel<<<(total + 255) / 256, 256, 0, stream>>>(W_ih, W_hh, b_ih, b_hh, Wc, bsum);
  lstm_ln_kernel<<<NB, 256, 0, stream>>>(X, lengths, Wc, bsum, gamma, beta, out);
}

// Round 2
// 6817.126 us; speedup vs baseline: 3.0178x; 3.0178x over previous
//
#include <hip/hip_runtime.h>

// Problem constants (match reference)
#define NB 512   // batch
#define NT 512   // time
#define NI 128   // input dim
#define NH 256   // hidden dim
#define NG 1024  // 4*NH gate rows
#define NKW 384  // NI + NH fused K
#define NKB 48   // NKW / 8 k-blocks
#define EPSV 1e-5f

__device__ __forceinline__ unsigned short f32_to_bf16(float f) {
  unsigned int u = __float_as_uint(f);
  u += 0x7fffu + ((u >> 16) & 1u);   // round-to-nearest-even
  return (unsigned short)(u >> 16);
}
__device__ __forceinline__ float bf_lo(unsigned int u) { return __uint_as_float(u << 16); }
__device__ __forceinline__ float bf_hi(unsigned int u) { return __uint_as_float(u & 0xffff0000u); }

// ---------------------------------------------------------------------------
// Prep 1: coalesced-blocked bf16 weights.
// Layout: Wb[kb][row][e], kb in [0,48), row in [0,1024), e in [0,8).
// One row-chunk = 8 bf16 = 16 B = one uint4; lane j reads row j -> lanes are
// 16 B apart -> fully coalesced wave loads.
// Also bsum = b_ih + b_hh.
// ---------------------------------------------------------------------------
__global__ void prep_kernel(const float* __restrict__ W_ih, const float* __restrict__ W_hh,
                            const float* __restrict__ b_ih, const float* __restrict__ b_hh,
                            unsigned short* __restrict__ Wb, float* __restrict__ bsum) {
  int idx = blockIdx.x * blockDim.x + threadIdx.x;   // over 48*1024*8 elements
  if (idx < NKB * NG * 8) {
    int e   = idx & 7;
    int row = (idx >> 3) & (NG - 1);
    int kb  = idx >> 13;
    int k = kb * 8 + e;
    float w = (k < NI) ? W_ih[row * NI + k] : W_hh[row * NH + (k - NI)];
    Wb[idx] = f32_to_bf16(w);
  }
  if (idx < NG) bsum[idx] = b_ih[idx] + b_hh[idx];
}

// ---------------------------------------------------------------------------
// Prep 2: rank-sort sequences by length (descending) -> perm.
// 512 elements, one block, O(N^2)/512 comparisons per thread.
// ---------------------------------------------------------------------------
__global__ void sort_kernel(const int* __restrict__ lengths, int* __restrict__ perm) {
  int i = threadIdx.x;
  __shared__ int L[NB];
  int li = lengths[i];
  L[i] = li;
  __syncthreads();
  int r = 0;
  for (int k = 0; k < NB; ++k) {
    int lk = L[k];
    r += (lk > li) || (lk == li && k < i);
  }
  perm[r] = i;
}

// ---------------------------------------------------------------------------
// Main: one block per PAIR of sequences (sorted neighbors). 256 threads;
// thread j owns hidden index j for both sequences. Weight chunk is unpacked
// once and used for both sequences (halves weight bytes per seq-step).
// ---------------------------------------------------------------------------
__global__ __launch_bounds__(256, 1)
void lstm_ln_kernel(const float* __restrict__ X, const int* __restrict__ lengths,
                    const int* __restrict__ perm,
                    const uint4* __restrict__ Wq, const float* __restrict__ bsum,
                    const float* __restrict__ gamma, const float* __restrict__ beta,
                    float* __restrict__ out) {
  const int p = blockIdx.x;
  const int j = threadIdx.x;

  const int b0 = perm[2 * p];
  const int b1 = perm[2 * p + 1];
  const int len0 = lengths[b0];
  const int len1 = lengths[b1];
  const int lmax = (len0 > len1) ? len0 : len1;

  __shared__ alignas(16) float xh0[NKW];   // [0,NI)=x_t seq0, [NI,NKW)=h seq0
  __shared__ alignas(16) float xh1[NKW];
  __shared__ float red[16];

  const float bs0 = bsum[0 * NH + j];
  const float bs1 = bsum[1 * NH + j];
  const float bs2 = bsum[2 * NH + j];
  const float bs3 = bsum[3 * NH + j];

  float c0 = 0.f, h0 = 0.f, c1 = 0.f, h1 = 0.f;
  xh0[NI + j] = 0.f;
  xh1[NI + j] = 0.f;

  const float* __restrict__ xrow0 = X + (size_t)b0 * NT * NI;
  const float* __restrict__ xrow1 = X + (size_t)b1 * NT * NI;

  for (int t = 0; t < lmax; ++t) {
    if (j < NI) xh0[j] = xrow0[(size_t)t * NI + j];
    else        xh1[j - NI] = xrow1[(size_t)t * NI + (j - NI)];
    __syncthreads();  // x staged AND h from prev step visible

    float a0 = bs0, a1 = bs1, a2 = bs2, a3 = bs3;   // seq0 gates
    float e0 = bs0, e1 = bs1, e2 = bs2, e3 = bs3;   // seq1 gates
    const float4* xv0 = (const float4*)xh0;
    const float4* xv1 = (const float4*)xh1;

#pragma unroll 2
    for (int kb = 0; kb < NKB; ++kb) {
      uint4 u0 = Wq[(size_t)kb * NG + 0 * NH + j];
      uint4 u1 = Wq[(size_t)kb * NG + 1 * NH + j];
      uint4 u2 = Wq[(size_t)kb * NG + 2 * NH + j];
      uint4 u3 = Wq[(size_t)kb * NG + 3 * NH + j];
      float4 xa0 = xv0[2 * kb], xb0 = xv0[2 * kb + 1];
      float4 xa1 = xv1[2 * kb], xb1 = xv1[2 * kb + 1];

#define GACC(u, accA, accB)                                              \
      {                                                                  \
        float w0 = bf_lo(u.x), w1 = bf_hi(u.x);                          \
        float w2 = bf_lo(u.y), w3 = bf_hi(u.y);                          \
        float w4 = bf_lo(u.z), w5 = bf_hi(u.z);                          \
        float w6 = bf_lo(u.w), w7 = bf_hi(u.w);                          \
        accA += w0 * xa0.x + w1 * xa0.y + w2 * xa0.z + w3 * xa0.w        \
              + w4 * xb0.x + w5 * xb0.y + w6 * xb0.z + w7 * xb0.w;       \
        accB += w0 * xa1.x + w1 * xa1.y + w2 * xa1.z + w3 * xa1.w        \
              + w4 * xb1.x + w5 * xb1.y + w6 * xb1.z + w7 * xb1.w;       \
      }
      GACC(u0, a0, e0)
      GACC(u1, a1, e1)
      GACC(u2, a2, e2)
      GACC(u3, a3, e3)
#undef GACC
    }

    // gate order [i, f, g, o]; sigmoid/tanh via exp2-backed __expf
    {
      float ig = 1.f / (1.f + __expf(-a0));
      float fg = 1.f / (1.f + __expf(-a1));
      float gg = 1.f - 2.f / (1.f + __expf(2.f * a2));
      float og = 1.f / (1.f + __expf(-a3));
      float cn = fg * c0 + ig * gg;
      float hn = og * (1.f - 2.f / (1.f + __expf(2.f * cn)));
      if (t < len0) { c0 = cn; h0 = hn; }
    }
    {
      float ig = 1.f / (1.f + __expf(-e0));
      float fg = 1.f / (1.f + __expf(-e1));
      float gg = 1.f - 2.f / (1.f + __expf(2.f * e2));
      float og = 1.f / (1.f + __expf(-e3));
      float cn = fg * c1 + ig * gg;
      float hn = og * (1.f - 2.f / (1.f + __expf(2.f * cn)));
      if (t < len1) { c1 = cn; h1 = hn; }
    }

    __syncthreads();  // everyone done reading old h
    xh0[NI + j] = h0;
    xh1[NI + j] = h1;
  }

  // ---- LayerNorm over H=256 for both sequences ----
  float s0 = h0, q0 = h0 * h0, s1 = h1, q1 = h1 * h1;
#pragma unroll
  for (int off = 32; off > 0; off >>= 1) {
    s0 += __shfl_xor(s0, off);
    q0 += __shfl_xor(q0, off);
    s1 += __shfl_xor(s1, off);
    q1 += __shfl_xor(q1, off);
  }
  int wid = j >> 6;
  int lane = j & 63;
  __syncthreads();
  if (lane == 0) {
    red[wid] = s0; red[4 + wid] = q0;
    red[8 + wid] = s1; red[12 + wid] = q1;
  }
  __syncthreads();
  if (j == 0) {
    float S0 = red[0] + red[1] + red[2] + red[3];
    float Q0 = red[4] + red[5] + red[6] + red[7];
    float S1 = red[8] + red[9] + red[10] + red[11];
    float Q1 = red[12] + red[13] + red[14] + red[15];
    float mu0 = S0 * (1.f / NH);
    float mu1 = S1 * (1.f / NH);
    red[0] = mu0;
    red[1] = rsqrtf(Q0 * (1.f / NH) - mu0 * mu0 + EPSV);
    red[2] = mu1;
    red[3] = rsqrtf(Q1 * (1.f / NH) - mu1 * mu1 + EPSV);
  }
  __syncthreads();
  float g = gamma[j], be = beta[j];
  out[(size_t)b0 * NH + j] = (h0 - red[0]) * red[1] * g + be;
  out[(size_t)b1 * NH + j] = (h1 - red[2]) * red[3] * g + be;
}

extern "C" void kernel_launch(void* const* d_in, const int* in_sizes, int n_in,
                              void* d_out, int out_size, void* d_ws, size_t ws_size,
                              hipStream_t stream) {
  const float* X       = (const float*)d_in[0];
  const int*   lengths = (const int*)d_in[1];
  const float* W_ih    = (const float*)d_in[2];
  const float* W_hh    = (const float*)d_in[3];
  const float* b_ih    = (const float*)d_in[4];
  const float* b_hh    = (const float*)d_in[5];
  const float* gamma   = (const float*)d_in[6];
  const float* beta    = (const float*)d_in[7];
  float* out = (float*)d_out;

  // workspace layout
  unsigned short* Wb = (unsigned short*)d_ws;                                   // 768 KB
  float* bsum = (float*)((char*)d_ws + (size_t)NKB * NG * 8 * sizeof(unsigned short)); // 4 KB
  int* perm = (int*)((char*)bsum + NG * sizeof(float));                          // 2 KB

  int total = NKB * NG * 8;
  prep_kernel<<<(total + 255) / 256, 256, 0, stream>>>(W_ih, W_hh, b_ih, b_hh, Wb, bsum);
  sort_kernel<<<1, NB, 0, stream>>>(lengths, perm);
  lstm_ln_kernel<<<NB / 2, 256, 0, stream>>>(X, lengths, perm, (const uint4*)Wb, bsum,
                                             gamma, beta, out);
}

// Round 3
// 5984.990 us; speedup vs baseline: 3.4374x; 1.1390x over previous
//
#include <hip/hip_runtime.h>

// Problem constants (match reference)
#define NB 512   // batch
#define NT 512   // time
#define NI 128   // input dim
#define NH 256   // hidden dim
#define NG 1024  // 4*NH gate rows
#define NKW 384  // NI + NH fused K
#define NKB 48   // NKW / 8 k-blocks
#define EPSV 1e-5f

__device__ __forceinline__ unsigned short f32_to_bf16(float f) {
  unsigned int u = __float_as_uint(f);
  u += 0x7fffu + ((u >> 16) & 1u);   // round-to-nearest-even
  return (unsigned short)(u >> 16);
}
__device__ __forceinline__ float bf_lo(unsigned int u) { return __uint_as_float(u << 16); }
__device__ __forceinline__ float bf_hi(unsigned int u) { return __uint_as_float(u & 0xffff0000u); }

// ---------------------------------------------------------------------------
// Prep 1: coalesced-blocked bf16 weights.
// Layout: Wb[kb][row][e], kb in [0,48), row in [0,1024), e in [0,8).
// One row-chunk = 8 bf16 = 16 B = one uint4; lane j reads row j -> lanes are
// 16 B apart -> fully coalesced wave loads.  Also bsum = b_ih + b_hh.
// ---------------------------------------------------------------------------
__global__ void prep_kernel(const float* __restrict__ W_ih, const float* __restrict__ W_hh,
                            const float* __restrict__ b_ih, const float* __restrict__ b_hh,
                            unsigned short* __restrict__ Wb, float* __restrict__ bsum) {
  int idx = blockIdx.x * blockDim.x + threadIdx.x;   // over 48*1024*8 elements
  if (idx < NKB * NG * 8) {
    int e   = idx & 7;
    int row = (idx >> 3) & (NG - 1);
    int kb  = idx >> 13;
    int k = kb * 8 + e;
    float w = (k < NI) ? W_ih[row * NI + k] : W_hh[row * NH + (k - NI)];
    Wb[idx] = f32_to_bf16(w);
  }
  if (idx < NG) bsum[idx] = b_ih[idx] + b_hh[idx];
}

// ---------------------------------------------------------------------------
// Prep 2: rank-sort sequences by length (descending) -> perm.
// ---------------------------------------------------------------------------
__global__ void sort_kernel(const int* __restrict__ lengths, int* __restrict__ perm) {
  int i = threadIdx.x;
  __shared__ int L[NB];
  int li = lengths[i];
  L[i] = li;
  __syncthreads();
  int r = 0;
  for (int k = 0; k < NB; ++k) {
    int lk = L[k];
    r += (lk > li) || (lk == li && k < i);
  }
  perm[r] = i;
}

// ---------------------------------------------------------------------------
// Main: one block (1024 threads = 16 waves) per PAIR of sorted sequences.
// Thread tid owns gate row tid (= gate q=tid>>8 of hidden unit tid&255) and
// computes its K=384 dot for BOTH sequences (weights unpacked once).
// Preactivations exchanged through LDS; threads 0..511 do the pointwise
// LSTM cell update, keeping c in-register.
// ---------------------------------------------------------------------------
__global__ __launch_bounds__(1024)
void lstm_ln_kernel(const float* __restrict__ X, const int* __restrict__ lengths,
                    const int* __restrict__ perm,
                    const uint4* __restrict__ Wq, const float* __restrict__ bsum,
                    const float* __restrict__ gamma, const float* __restrict__ beta,
                    float* __restrict__ out) {
  const int p = blockIdx.x;
  const int tid = threadIdx.x;

  __shared__ alignas(16) float xh0[NKW];   // [0,NI)=x_t, [NI,NKW)=h   (seq0)
  __shared__ alignas(16) float xh1[NKW];   // (seq1)
  __shared__ float g0[NG];                 // gate preactivations seq0
  __shared__ float g1[NG];                 // gate preactivations seq1
  __shared__ float red[24];

  const int b0 = perm[2 * p];
  const int b1 = perm[2 * p + 1];
  const int len0 = lengths[b0];
  const int len1 = lengths[b1];
  const int lmax = (len0 > len1) ? len0 : len1;

  const float bs = bsum[tid];              // bias for row tid

  // unit-update mapping (valid for tid < 512)
  const int s = tid >> 8;                  // 0: seq0, 1: seq1
  const int j = tid & 255;                 // hidden unit
  const int mylen = s ? len1 : len0;

  float c = 0.f, h = 0.f;

  if (tid < 256) xh0[NI + tid] = 0.f;
  else if (tid < 512) xh1[NI + (tid - 256)] = 0.f;

  const float* __restrict__ xrow0 = X + (size_t)b0 * NT * NI;
  const float* __restrict__ xrow1 = X + (size_t)b1 * NT * NI;

  for (int t = 0; t < lmax; ++t) {
    if (tid < NI)          xh0[tid] = xrow0[(size_t)t * NI + tid];
    else if (tid < 2 * NI) xh1[tid - NI] = xrow1[(size_t)t * NI + (tid - NI)];
    __syncthreads();   // x_t staged AND h from prev step visible

    float a0 = bs, a1 = bs;
    const float4* xv0 = (const float4*)xh0;
    const float4* xv1 = (const float4*)xh1;
#pragma unroll 4
    for (int kb = 0; kb < NKB; ++kb) {
      uint4 u = Wq[(size_t)kb * NG + tid];
      float4 xa0 = xv0[2 * kb], xb0 = xv0[2 * kb + 1];
      float4 xa1 = xv1[2 * kb], xb1 = xv1[2 * kb + 1];
      float w0 = bf_lo(u.x), w1 = bf_hi(u.x);
      float w2 = bf_lo(u.y), w3 = bf_hi(u.y);
      float w4 = bf_lo(u.z), w5 = bf_hi(u.z);
      float w6 = bf_lo(u.w), w7 = bf_hi(u.w);
      a0 += w0 * xa0.x + w1 * xa0.y + w2 * xa0.z + w3 * xa0.w
          + w4 * xb0.x + w5 * xb0.y + w6 * xb0.z + w7 * xb0.w;
      a1 += w0 * xa1.x + w1 * xa1.y + w2 * xa1.z + w3 * xa1.w
          + w4 * xb1.x + w5 * xb1.y + w6 * xb1.z + w7 * xb1.w;
    }
    g0[tid] = a0;
    g1[tid] = a1;
    __syncthreads();   // gates visible; all xh reads of this step done

    if (tid < 512) {
      const float* __restrict__ gg = s ? g1 : g0;
      float pi = gg[j], pf = gg[NH + j], pg = gg[2 * NH + j], po = gg[3 * NH + j];
      if (t < mylen) {
        float ig = 1.f / (1.f + __expf(-pi));
        float fg = 1.f / (1.f + __expf(-pf));
        float gv = 1.f - 2.f / (1.f + __expf(2.f * pg));
        float og = 1.f / (1.f + __expf(-po));
        c = fg * c + ig * gv;
        h = og * (1.f - 2.f / (1.f + __expf(2.f * c)));
        if (s) xh1[NI + j] = h;
        else   xh0[NI + j] = h;
      }
    }
    // next iteration's first __syncthreads orders these writes vs. reads
  }

  __syncthreads();

  // ---- LayerNorm over H=256 per sequence (4 waves each, tid<512) ----
  float sum = h, sq = h * h;
#pragma unroll
  for (int off = 32; off > 0; off >>= 1) {
    sum += __shfl_xor(sum, off);
    sq  += __shfl_xor(sq, off);
  }
  int wid = tid >> 6;     // 0..7 hold seq data
  int lane = tid & 63;
  if (lane == 0 && wid < 8) { red[wid] = sum; red[8 + wid] = sq; }
  __syncthreads();
  if (tid == 0) {
    float S = red[0] + red[1] + red[2] + red[3];
    float Q = red[8] + red[9] + red[10] + red[11];
    float mu = S * (1.f / NH);
    red[16] = mu;
    red[17] = rsqrtf(Q * (1.f / NH) - mu * mu + EPSV);
  }
  if (tid == 256) {
    float S = red[4] + red[5] + red[6] + red[7];
    float Q = red[12] + red[13] + red[14] + red[15];
    float mu = S * (1.f / NH);
    red[18] = mu;
    red[19] = rsqrtf(Q * (1.f / NH) - mu * mu + EPSV);
  }
  __syncthreads();
  if (tid < 512) {
    float mu = red[16 + 2 * s], rstd = red[17 + 2 * s];
    int b = s ? b1 : b0;
    out[(size_t)b * NH + j] = (h - mu) * rstd * gamma[j] + beta[j];
  }
}

extern "C" void kernel_launch(void* const* d_in, const int* in_sizes, int n_in,
                              void* d_out, int out_size, void* d_ws, size_t ws_size,
                              hipStream_t stream) {
  const float* X       = (const float*)d_in[0];
  const int*   lengths = (const int*)d_in[1];
  const float* W_ih    = (const float*)d_in[2];
  const float* W_hh    = (const float*)d_in[3];
  const float* b_ih    = (const float*)d_in[4];
  const float* b_hh    = (const float*)d_in[5];
  const float* gamma   = (const float*)d_in[6];
  const float* beta    = (const float*)d_in[7];
  float* out = (float*)d_out;

  // workspace layout
  unsigned short* Wb = (unsigned short*)d_ws;                                        // 768 KB
  float* bsum = (float*)((char*)d_ws + (size_t)NKB * NG * 8 * sizeof(unsigned short)); // 4 KB
  int* perm = (int*)((char*)bsum + NG * sizeof(float));                               // 2 KB

  int total = NKB * NG * 8;
  prep_kernel<<<(total + 255) / 256, 256, 0, stream>>>(W_ih, W_hh, b_ih, b_hh, Wb, bsum);
  sort_kernel<<<1, NB, 0, stream>>>(lengths, perm);
  lstm_ln_kernel<<<NB / 2, 1024, 0, stream>>>(X, lengths, perm, (const uint4*)Wb, bsum,
                                              gamma, beta, out);
}